// Round 5
// baseline (149.073 us; speedup 1.0000x reference)
//
#include <hip/hip_runtime.h>
#include <math.h>

#define HIDDEN 256
#define NHEADS 8
#define HEAD 32
#define NTOK 2048      // tokens per batch (8*16*16)
#define NBIAS 115320   // 8 * 15 * 31 * 31
#define HTAB 14415     // 15*31*31 per-head bias entries

typedef __attribute__((ext_vector_type(8))) __bf16 bf16x8;
typedef __attribute__((ext_vector_type(4))) float f32x4;
typedef __attribute__((ext_vector_type(16))) float f32x16;
typedef __attribute__((ext_vector_type(4))) unsigned uint32x4;

static __device__ __forceinline__ f32x4 mfma16(bf16x8 a, bf16x8 b, f32x4 c) {
    return __builtin_amdgcn_mfma_f32_16x16x32_bf16(a, b, c, 0, 0, 0);
}
static __device__ __forceinline__ f32x16 mfma32(bf16x8 a, bf16x8 b, f32x16 c) {
    return __builtin_amdgcn_mfma_f32_32x32x16_bf16(a, b, c, 0, 0, 0);
}
static __device__ __forceinline__ float fexp2(float x) {
#if __has_builtin(__builtin_amdgcn_exp2f)
    return __builtin_amdgcn_exp2f(x);
#else
    return exp2f(x);
#endif
}
static __device__ __forceinline__ unsigned pkbf16(float a, float b) {
    unsigned short ua = __builtin_bit_cast(unsigned short, (__bf16)a);
    unsigned short ub = __builtin_bit_cast(unsigned short, (__bf16)b);
    return (unsigned)ua | ((unsigned)ub << 16);
}

// ---------------- kernel 0a: x fp32 -> bf16 ----------------
__global__ void k_cvt_x(const float* __restrict__ x, __bf16* __restrict__ xb) {
    int i = (blockIdx.x * blockDim.x + threadIdx.x) * 4;
    float4 v = *(const float4*)(x + i);
    xb[i + 0] = (__bf16)v.x;
    xb[i + 1] = (__bf16)v.y;
    xb[i + 2] = (__bf16)v.z;
    xb[i + 3] = (__bf16)v.w;
}

// ---------------- kernel 0b: W fp32 -> bf16, transposed (N x K) ----------------
__global__ void k_cvt_w(const float* __restrict__ w0, const float* __restrict__ w1,
                        const float* __restrict__ w2, const float* __restrict__ w3,
                        __bf16* __restrict__ t0, __bf16* __restrict__ t1,
                        __bf16* __restrict__ t2, __bf16* __restrict__ t3) {
    int wsel = blockIdx.x >> 8;
    int i = (blockIdx.x & 255) * 256 + threadIdx.x;
    const float* w = (wsel == 0) ? w0 : (wsel == 1) ? w1 : (wsel == 2) ? w2 : w3;
    __bf16* t = (wsel == 0) ? t0 : (wsel == 1) ? t1 : (wsel == 2) ? t2 : t3;
    int n = i >> 8, k = i & 255;
    t[i] = (__bf16)w[k * 256 + n];       // t[n][k] = W[k][n]
}

// ---------------- kernel 0c: reversed f32 bias quads, log2e folded ----------------
// btq[head][i] = float4 {bt[i+3], bt[i+2], bt[i+1], bt[i]} * log2e:
// a 16B load at J-3 yields element r = bt[J-r] (descending run, fragment regs r=0..3),
// landing directly in the MFMA C-init registers (no unpack VALU).
__global__ void k_cvt_biasq(const float* __restrict__ bias, float4* __restrict__ btq) {
    int i = blockIdx.x * 256 + threadIdx.x;
    if (i >= NBIAS) return;
    int head = i / HTAB;
    int off = i - head * HTAB;
    int b0 = head * HTAB;
    const float L2E = 1.4426950408889634f;
    int i3 = off + 3 > HTAB - 1 ? HTAB - 1 : off + 3;
    int i2 = off + 2 > HTAB - 1 ? HTAB - 1 : off + 2;
    int i1 = off + 1 > HTAB - 1 ? HTAB - 1 : off + 1;
    btq[i] = make_float4(bias[b0 + i3] * L2E, bias[b0 + i2] * L2E,
                         bias[b0 + i1] * L2E, bias[b0 + off] * L2E);
}

// ---------------- kernel 1: fused QKV projection ----------------
__global__ __launch_bounds__(256) void k_qkv(const __bf16* __restrict__ xb,
                                             const __bf16* __restrict__ wqT,
                                             const __bf16* __restrict__ wkT,
                                             const __bf16* __restrict__ wvT,
                                             __bf16* __restrict__ qb,
                                             __bf16* __restrict__ kb,
                                             __bf16* __restrict__ vb) {
    int wid = blockIdx.x * 4 + (threadIdx.x >> 6);
    int lane = threadIdx.x & 63;
    int g = wid % 12, mt = wid / 12;
    int lm = lane & 15, lg = lane >> 4, lk = lg * 8;
    int which = g >> 2;
    int nc0 = (g & 3) * 64;
    const __bf16* wT = (which == 0) ? wqT : (which == 1) ? wkT : wvT;

    f32x4 acc[4];
#pragma unroll
    for (int j = 0; j < 4; ++j) acc[j] = (f32x4){0.f, 0.f, 0.f, 0.f};

    const __bf16* arow = xb + (size_t)(mt * 16 + lm) * 256 + lk;
    const __bf16* brow = wT + (size_t)(nc0 + lm) * 256 + lk;
#pragma unroll
    for (int kk = 0; kk < 8; ++kk) {
        bf16x8 a = *(const bf16x8*)(arow + kk * 32);
#pragma unroll
        for (int j = 0; j < 4; ++j) {
            bf16x8 b = *(const bf16x8*)(brow + (size_t)j * 16 * 256 + kk * 32);
            acc[j] = mfma16(a, b, acc[j]);
        }
    }
    const float QS = 0.17677669529663687f * 1.4426950408889634f;  // 1/sqrt(32) * log2(e)
#pragma unroll
    for (int j = 0; j < 4; ++j) {
        int col = nc0 + j * 16 + lm;
        int h = col >> 5, d = col & 31;
#pragma unroll
        for (int r = 0; r < 4; ++r) {
            int row = mt * 16 + lg * 4 + r;
            int b_ = row >> 11, n = row & 2047;
            if (which == 0)      qb[((size_t)(b_ * 8 + h) * 2048 + n) * 32 + d] = (__bf16)(acc[j][r] * QS);
            else if (which == 1) kb[((size_t)(b_ * 8 + h) * 2048 + n) * 32 + d] = (__bf16)acc[j][r];
            else                 vb[((size_t)(b_ * 8 + h) * 32 + d) * 2048 + n] = (__bf16)acc[j][r]; // V^T
        }
    }
}

// ---------------- kernel 2: attention, 32x32 swapped-operand, pipelined ----------
// Block = one (b,h,q-strip of 32 rows); 4 waves = 4-way k-split (512 k each).
// S^T = mfma32(K, Q) with C-init = f32 bias quads loaded straight from memory.
// P in-register -> bf16 pack -> PV via token-order-matched V^T loads (no permute).
// 1-deep software pipeline: iter+1's bias+K loads issued before iter's compute.
__global__ __launch_bounds__(256) void k_attn(const __bf16* __restrict__ qb,
                                              const __bf16* __restrict__ kb,
                                              const __bf16* __restrict__ vb,
                                              const float4* __restrict__ btqall,
                                              __bf16* __restrict__ attn) {
    int bid = blockIdx.x;
    int bh = bid >> 6;          // 0..31
    int qs = bid & 63;          // q-strip 0..63
    int b_ = bh >> 3, h = bh & 7;
    int w = threadIdx.x >> 6;   // wave = k-quarter
    int lane = threadIdx.x & 63;
    int lq = lane & 31;
    int hf = lane >> 5;
    int q0 = qs * 32;

    const __bf16* qbase = qb + (size_t)bh * NTOK * 32;
    const __bf16* kbase = kb + (size_t)bh * NTOK * 32;
    const __bf16* vbase = vb + (size_t)bh * 32 * NTOK;
    const float4* btq = btqall + h * HTAB;

    // Q B-frags (col=lane&31=q, k=8*hf+j), d-chunks 0 and 1 — loop invariant
    bf16x8 qf0 = *(const bf16x8*)(qbase + (size_t)(q0 + lq) * 32 + hf * 8);
    bf16x8 qf1 = *(const bf16x8*)(qbase + (size_t)(q0 + lq) * 32 + 16 + hf * 8);

    int qg = q0 + lq;
    // loop-invariant part of bias index J (includes -4hf of the k-token code)
    int qidx4 = (qg >> 8) * 961 + ((qg >> 4) & 15) * 31 + (qg & 15) + 7207 - 4 * hf;

    f32x16 Oacc, Lacc;
#pragma unroll
    for (int j = 0; j < 16; ++j) { Oacc[j] = 0.f; Lacc[j] = 0.f; }

    bf16x8 ones;
#pragma unroll
    for (int j = 0; j < 8; ++j) ones[j] = (__bf16)1.0f;

    // ---- pipeline registers: bias quads + K frags for the CURRENT iter ----
    f32x4 cb0, cb1, cb2, cb3;
    bf16x8 ck0, ck1;
    {
        int t0 = w * 512;
        int c00 = (t0 >> 8) * 961 + ((t0 >> 4) & 15) * 31;
        int jb = qidx4 - c00;
        cb0 = *(const f32x4*)&btq[jb - 3];
        cb1 = *(const f32x4*)&btq[jb - 11];
        cb2 = *(const f32x4*)&btq[jb - 34];
        cb3 = *(const f32x4*)&btq[jb - 42];
        const __bf16* kp = kbase + (size_t)(t0 + lq) * 32 + hf * 8;
        ck0 = *(const bf16x8*)(kp);
        ck1 = *(const bf16x8*)(kp + 16);
    }

#pragma unroll
    for (int it = 0; it < 16; ++it) {
        int t0 = w * 512 + it * 32;

        // ---- prefetch iter+1 (issued before any use of current loads) ----
        f32x4 nb0, nb1, nb2, nb3;
        bf16x8 nk0, nk1;
        if (it < 15) {
            int t1 = t0 + 32;
            int c01 = (t1 >> 8) * 961 + ((t1 >> 4) & 15) * 31;
            int jb1 = qidx4 - c01;
            nb0 = *(const f32x4*)&btq[jb1 - 3];
            nb1 = *(const f32x4*)&btq[jb1 - 11];
            nb2 = *(const f32x4*)&btq[jb1 - 34];
            nb3 = *(const f32x4*)&btq[jb1 - 42];
            const __bf16* kp1 = kbase + (size_t)(t1 + lq) * 32 + hf * 8;
            nk0 = *(const bf16x8*)(kp1);
            nk1 = *(const bf16x8*)(kp1 + 16);
        }

        // ---- V^T loads for THIS iter (consumed at the end of the iteration) ----
        // element j <- token t0 + 4hf + 8*(j>>2) + (j&3)  (matches P's in-lane order)
        const __bf16* vp = vbase + (size_t)lq * NTOK + t0 + 4 * hf;
        uint2 va = *(const uint2*)(vp);
        uint2 vbq = *(const uint2*)(vp + 8);
        uint2 vc = *(const uint2*)(vp + 16);
        uint2 vd = *(const uint2*)(vp + 24);
        uint32x4 vw0 = {va.x, va.y, vbq.x, vbq.y};
        uint32x4 vw1 = {vc.x, vc.y, vd.x, vd.y};
        bf16x8 vf0 = __builtin_bit_cast(bf16x8, vw0);
        bf16x8 vf1 = __builtin_bit_cast(bf16x8, vw1);

        // ---- S = bias-init, then QK^T MFMA ----
        f32x16 S;
        S[0]  = cb0[0]; S[1]  = cb0[1]; S[2]  = cb0[2]; S[3]  = cb0[3];
        S[4]  = cb1[0]; S[5]  = cb1[1]; S[6]  = cb1[2]; S[7]  = cb1[3];
        S[8]  = cb2[0]; S[9]  = cb2[1]; S[10] = cb2[2]; S[11] = cb2[3];
        S[12] = cb3[0]; S[13] = cb3[1]; S[14] = cb3[2]; S[15] = cb3[3];
        S = mfma32(ck0, qf0, S);
        S = mfma32(ck1, qf1, S);

        // ---- P = exp2(S) -> packed bf16 pairs ----
        unsigned W0 = pkbf16(fexp2(S[0]),  fexp2(S[1]));
        unsigned W1 = pkbf16(fexp2(S[2]),  fexp2(S[3]));
        unsigned W2 = pkbf16(fexp2(S[4]),  fexp2(S[5]));
        unsigned W3 = pkbf16(fexp2(S[6]),  fexp2(S[7]));
        unsigned W4 = pkbf16(fexp2(S[8]),  fexp2(S[9]));
        unsigned W5 = pkbf16(fexp2(S[10]), fexp2(S[11]));
        unsigned W6 = pkbf16(fexp2(S[12]), fexp2(S[13]));
        unsigned W7 = pkbf16(fexp2(S[14]), fexp2(S[15]));
        uint32x4 pw0 = {W0, W1, W2, W3};
        uint32x4 pw1 = {W4, W5, W6, W7};
        bf16x8 pf0 = __builtin_bit_cast(bf16x8, pw0);
        bf16x8 pf1 = __builtin_bit_cast(bf16x8, pw1);

        Oacc = mfma32(vf0, pf0, Oacc);   // O^T[d][q] += V^T . P (common token perm)
        Oacc = mfma32(vf1, pf1, Oacc);
        Lacc = mfma32(ones, pf0, Lacc);  // every reg = lsum[q] partial
        Lacc = mfma32(ones, pf1, Lacc);

        // ---- rotate pipeline ----
        if (it < 15) {
            cb0 = nb0; cb1 = nb1; cb2 = nb2; cb3 = nb3;
            ck0 = nk0; ck1 = nk1;
        }
    }

    // ---- combine 4 k-partials via LDS ----
    __shared__ float part[4][64][17];   // 16 O + 1 lsum; stride 17 (odd -> bank-friendly)
#pragma unroll
    for (int j = 0; j < 4; ++j) {
        float4 t;
        t.x = Oacc[4 * j]; t.y = Oacc[4 * j + 1]; t.z = Oacc[4 * j + 2]; t.w = Oacc[4 * j + 3];
        *(float4*)&part[w][lane][4 * j] = t;
    }
    part[w][lane][16] = Lacc[0];
    __syncthreads();

    float4 o = {0.f, 0.f, 0.f, 0.f};
    float ls = 0.f;
#pragma unroll
    for (int sw = 0; sw < 4; ++sw) {
        float4 t = *(const float4*)&part[sw][lane][4 * w];
        o.x += t.x; o.y += t.y; o.z += t.z; o.w += t.w;
        ls += part[sw][lane][16];
    }
    float inv = 1.0f / ls;
    // wave w keeps regs 4w..4w+3 -> d = r + 8w + 4hf
    unsigned lo = pkbf16(o.x * inv, o.y * inv);
    unsigned hi = pkbf16(o.z * inv, o.w * inv);
    size_t base = ((size_t)b_ * NTOK + q0 + lq) * 256 + h * 32 + 8 * w + 4 * hf;
    *(uint2*)(attn + base) = make_uint2(lo, hi);
}

// ---------------- kernel 3: output projection -> fp32 ----------------
__global__ __launch_bounds__(256) void k_out(const __bf16* __restrict__ attn,
                                             const __bf16* __restrict__ woT,
                                             float* __restrict__ out) {
    int wid = blockIdx.x * 4 + (threadIdx.x >> 6);
    int lane = threadIdx.x & 63;
    int ng = wid & 3, mt = wid >> 2;
    int lm = lane & 15, lg = lane >> 4, lk = lg * 8;
    int nc0 = ng * 64;

    f32x4 acc[4];
#pragma unroll
    for (int j = 0; j < 4; ++j) acc[j] = (f32x4){0.f, 0.f, 0.f, 0.f};

    const __bf16* arow = attn + (size_t)(mt * 16 + lm) * 256 + lk;
    const __bf16* brow = woT + (size_t)(nc0 + lm) * 256 + lk;
#pragma unroll
    for (int kk = 0; kk < 8; ++kk) {
        bf16x8 a = *(const bf16x8*)(arow + kk * 32);
#pragma unroll
        for (int j = 0; j < 4; ++j) {
            bf16x8 b = *(const bf16x8*)(brow + (size_t)j * 16 * 256 + kk * 32);
            acc[j] = mfma16(a, b, acc[j]);
        }
    }
#pragma unroll
    for (int j = 0; j < 4; ++j) {
        int col = nc0 + j * 16 + lm;
#pragma unroll
        for (int r = 0; r < 4; ++r) {
            int row = mt * 16 + lg * 4 + r;
            out[(size_t)row * 256 + col] = acc[j][r];
        }
    }
}

extern "C" void kernel_launch(void* const* d_in, const int* in_sizes, int n_in,
                              void* d_out, int out_size, void* d_ws, size_t ws_size,
                              hipStream_t stream) {
    const float* x    = (const float*)d_in[0];
    const float* Wq   = (const float*)d_in[1];
    const float* Wk   = (const float*)d_in[2];
    const float* Wv   = (const float*)d_in[3];
    const float* Wo   = (const float*)d_in[4];
    const float* bias = (const float*)d_in[5];
    float* out = (float*)d_out;

    __bf16* ws  = (__bf16*)d_ws;
    __bf16* xb  = ws;                       // 2,097,152 bf16 (reused as att)
    __bf16* wqT = xb  + 2097152;
    __bf16* wkT = wqT + 65536;
    __bf16* wvT = wkT + 65536;
    __bf16* woT = wvT + 65536;
    __bf16* qb  = woT + 65536;              // (b,h,n,32)
    __bf16* kb  = qb  + 2097152;            // (b,h,n,32)
    __bf16* vb  = kb  + 2097152;            // (b,h,32,n)  V^T
    float4* btq = (float4*)(vb + 2097152);  // 115320 x 16B f32 bias quads (16B-aligned)
    __bf16* att = xb;                       // alias: xb dead after k_qkv

    k_cvt_x<<<2048, 256, 0, stream>>>(x, xb);
    k_cvt_w<<<1024, 256, 0, stream>>>(Wq, Wk, Wv, Wo, wqT, wkT, wvT, woT);
    k_cvt_biasq<<<(NBIAS + 255) / 256, 256, 0, stream>>>(bias, btq);
    k_qkv<<<1536, 256, 0, stream>>>(xb, wqT, wkT, wvT, qb, kb, vb);
    k_attn<<<2048, 256, 0, stream>>>(qb, kb, vb, btq, att);
    k_out<<<512, 256, 0, stream>>>(att, woT, out);
}